// Round 9
// baseline (253.862 us; speedup 1.0000x reference)
//
#include <hip/hip_runtime.h>
#include <stdint.h>

// out[b,o,m] = sum_i in[b,i,m] * w[i,o,m]  (complex, fp32)
// B=32, Ci=Co=128, M=64*65=4160. One float2 per complex element.
//
// R9: SLACK probe. 256-thr blocks (4 waves) = 4 independent barrier
// domains per CU (16 waves/CU), vs R5/R8's 2 lockstep 8-wave blocks.
// Block = 32b x 32o x 8modes; thread tile 4b x 8o (64-reg acc).
// KC=4, double-buffered 2x16KB (32KB/block -> 4 blocks/CU).
// 4 x global_load_lds dwordx4 per thread/chunk, spread one per kk-phase
// of the PREVIOUS chunk (issue-to-need ~ 1 chunk >> HBM latency).
// One barrier per chunk (trailing barrier was redundant).
// W LDS layout two-level XOR swizzle, applied BOTH sides:
//   o_phys = o ^ ((o>>3)&1),  p = (ml>>1) ^ ((o>>3)&3)
// -> per-q wave read spans 16 8B bank-slots = 2-way (free).

typedef float f2 __attribute__((ext_vector_type(2)));

#define NB 32
#define CI 128
#define CO 128
#define OT 32
#define MODES 4160
#define MPB 8
#define KC 4
#define NCHUNK (CI / KC)               // 32
#define ABUF_F2 (KC * NB * MPB)        // 1024 f2 = 8 KB
#define WBUF_F2 (KC * OT * MPB)        // 1024 f2 = 8 KB
#define BUF_F2  (ABUF_F2 + WBUF_F2)    // 16 KB per buffer

// acc.lo += a.lo*w.lo - a.hi*w.hi ; acc.hi += a.lo*w.hi + a.hi*w.lo
#define CFMA(acc, av, wv)                                                      \
  asm("v_pk_fma_f32 %0, %1, %2, %0 op_sel:[0,0,0] op_sel_hi:[0,1,1]"           \
      : "+v"(acc) : "v"(av), "v"(wv));                                         \
  asm("v_pk_fma_f32 %0, %1, %2, %0 op_sel:[1,1,0] op_sel_hi:[1,0,1] "          \
      "neg_lo:[1,0,0]"                                                         \
      : "+v"(acc) : "v"(av), "v"(wv));

#define VM_WAIT(N) asm volatile("s_waitcnt vmcnt(" #N ")" ::: "memory")

__device__ __forceinline__ void gload16(const f2* g, f2* l) {
    __builtin_amdgcn_global_load_lds(
        (const __attribute__((address_space(1))) uint32_t*)g,
        (__attribute__((address_space(3))) uint32_t*)l, 16, 0, 0);
}

// Stage phase PH (0..3) of a K-chunk: one 16B DMA per thread.
// A (512 units, PH 0-1): unit j: kk=j>>7, b=(j>>2)&31, mlp=j&3 (linear).
// W (512 units, PH 2-3): unit j: kk=j>>7, o_phys=(j>>2)&31, p=j&3.
//   Physical unit holds global o = o_phys ^ ((o_phys>>3)&1),
//   ml-pair q_g = p ^ ((o_phys>>3)&3)   (bits 3-4 of o unchanged by XOR).
template <int PH>
__device__ __forceinline__ void stage_phase(const f2* __restrict__ Ig,
                                            const f2* __restrict__ Wl,
                                            f2* dst, int t, int m0,
                                            int obase, int k0) {
    if constexpr (PH < 2) {
        const int j  = PH * 256 + t;
        const int kk = j >> 7, b = (j >> 2) & 31, mlp = j & 3;
        gload16(Ig + (size_t)(b * CI + k0 + kk) * MODES + m0 + mlp * 2,
                dst + j * 2);
    } else {
        const int j   = (PH - 2) * 256 + t;
        const int kk  = j >> 7, oph = (j >> 2) & 31, p = j & 3;
        const int sw  = (oph >> 3) & 3;
        const int o   = oph ^ (sw & 1);
        const int qg  = p ^ sw;
        gload16(Wl + (size_t)((k0 + kk) * CO + obase + o) * MODES + m0 + qg * 2,
                dst + ABUF_F2 + j * 2);
    }
}

__global__ __launch_bounds__(256, 4)
void cmul2d_kernel(const f2* __restrict__ Ig,
                   const f2* __restrict__ Wl,
                   f2* __restrict__ Og) {
    __shared__ f2 lds[2 * BUF_F2];   // 32 KB -> 4 blocks/CU

    const int t = threadIdx.x;

    // XCD-chunked job map (2080 = 8 XCDs x 260): the 4 o-quarter blocks of
    // one mode-group are adjacent on one XCD -> I slice (256KB) L2-shared.
    const int bid   = blockIdx.x;
    const int jid   = (bid & 7) * 260 + (bid >> 3);
    const int mg    = jid >> 2;            // 0..519
    const int oq    = jid & 3;             // o-quarter
    const int m0    = mg * MPB;
    const int obase = oq * OT;

    const int ml = t & 7;      // mode lane
    const int s  = t >> 3;     // worker 0..31
    const int so = s & 3;      // o-group (8 o each); spans wave
    const int sb = s >> 2;     // b-group (4 b each)

    f2 acc[4][8];
#pragma unroll
    for (int r = 0; r < 4; ++r)
#pragma unroll
        for (int q = 0; q < 8; ++q) acc[r][q] = (f2)(0.0f);

    // read-side W swizzle pieces (constant per thread):
    const int pxor = (ml >> 1);            // ^ so applied per-q below (sw=so)

    // prologue: stage chunk 0 into buffer 0
    stage_phase<0>(Ig, Wl, lds, t, m0, obase, 0);
    stage_phase<1>(Ig, Wl, lds, t, m0, obase, 0);
    stage_phase<2>(Ig, Wl, lds, t, m0, obase, 0);
    stage_phase<3>(Ig, Wl, lds, t, m0, obase, 0);

#pragma unroll 1
    for (int c = 0; c < NCHUNK; ++c) {
        VM_WAIT(0);                        // own chunk-c loads (issued 1 chunk
        __builtin_amdgcn_s_barrier();      //  ago) retired; collective sync
        __builtin_amdgcn_sched_barrier(0);

        const f2* Ab = lds + (c & 1) * BUF_F2;
        const f2* Wb = Ab + ABUF_F2;
        f2* nbuf = lds + ((c + 1) & 1) * BUF_F2;   // readers done (barrier)
        const bool more = (c + 1 < NCHUNK);
        const int  nk0  = (c + 1) * KC;

#pragma unroll
        for (int kk = 0; kk < KC; ++kk) {
            f2 a[4], w[8];
#pragma unroll
            for (int r = 0; r < 4; ++r)    // 2-way + broadcast: free
                a[r] = Ab[kk * (NB * MPB) + (sb * 4 + r) * MPB + ml];
#pragma unroll
            for (int q = 0; q < 8; ++q) {  // swizzled: 16 slots, 2-way, free
                const int o   = so * 8 + q;
                const int oph = o ^ (so & 1);
                const int p   = pxor ^ so;
                w[q] = Wb[(kk * (OT * MPB)) + ((oph * 4 + p) << 1) + (ml & 1)];
            }
            if (more) {                    // spread DMA: 1 per kk-phase
                if (kk == 0) stage_phase<0>(Ig, Wl, nbuf, t, m0, obase, nk0);
                else if (kk == 1) stage_phase<1>(Ig, Wl, nbuf, t, m0, obase, nk0);
                else if (kk == 2) stage_phase<2>(Ig, Wl, nbuf, t, m0, obase, nk0);
                else stage_phase<3>(Ig, Wl, nbuf, t, m0, obase, nk0);
            }
            __builtin_amdgcn_s_setprio(1); // T5: favor FMA cluster
#pragma unroll
            for (int r = 0; r < 4; ++r)
#pragma unroll
                for (int q = 0; q < 8; ++q) {
                    CFMA(acc[r][q], a[r], w[q]);
                }
            __builtin_amdgcn_s_setprio(0);
        }
        // no trailing barrier: next iter's top barrier is the sync point
    }

    // epilogue: per (b,o) the 8 ml lanes are consecutive -> 64B segments
#pragma unroll
    for (int r = 0; r < 4; ++r) {
        const int b = sb * 4 + r;
#pragma unroll
        for (int q = 0; q < 8; ++q) {
            const int o = obase + so * 8 + q;
            Og[(size_t)(b * CO + o) * MODES + m0 + ml] = acc[r][q];
        }
    }
}

extern "C" void kernel_launch(void* const* d_in, const int* in_sizes, int n_in,
                              void* d_out, int out_size, void* d_ws, size_t ws_size,
                              hipStream_t stream) {
    const f2* I = (const f2*)d_in[0];
    const f2* W = (const f2*)d_in[1];
    f2* O = (f2*)d_out;
    dim3 grid(2080);    // 520 mode-groups x 4 o-quarters
    dim3 block(256);    // 4 waves = 1 independent barrier domain
    cmul2d_kernel<<<grid, block, 0, stream>>>(I, W, O);
}